// Round 8
// baseline (144.757 us; speedup 1.0000x reference)
//
#include <hip/hip_runtime.h>
#include <hip/hip_bf16.h>
#include <cfloat>

// B=32, N=2048 -> BN=65536 rows, D=128, K=1024 codes
#define DIM 128
#define NCODES 1024
#define MTILE 128            // rows per block = 4 waves x 32 rows
#define NSTEPS 32            // 1024 codes / 32 per step
#define TILE_BYTES 16384     // 32 codes x 128 k x 2 planes x 2 B
#define LOSS_SCALE (12.5f / 8388608.0f)

typedef _Float16 f16x8 __attribute__((ext_vector_type(8)));
typedef float f32x16 __attribute__((ext_vector_type(16)));

// prep: E (fp32) -> Epk packed for mfma_f32_32x32x16_f16 B-operand + enorm.
// Tile g = code>>5 (32 codes, 16 KB). B layout for 32x32x16: lane l holds
// B[k=(l>>5)*8+j][n=l&31], 8 f16 (4 VGPR). Per (ks=k/16, plane p) the 64-lane
// fragment is 1 KB, stored at tile_base + (ks*2+p)*1024 + lane*16 -> vq loads
// are contiguous coalesced 1 KB global_load_dwordx4. Block 0 zeroes loss.
__global__ __launch_bounds__(128) void prep_kernel(const float* __restrict__ E,
                                                   _Float16* __restrict__ Epk,
                                                   float* __restrict__ enorm,
                                                   float* __restrict__ loss) {
    const int k = blockIdx.x;   // code
    const int d = threadIdx.x;  // dim
    if (k == 0 && d == 0) *loss = 0.f;
    float e = E[k * DIM + d];
    _Float16 h = (_Float16)e;
    _Float16 l = (_Float16)(e - (float)h);
    const int g = k >> 5, n = k & 31;
    const int ks = d >> 4, hb = (d >> 3) & 1, j = d & 7;
    const int lane = hb * 32 + n;
    const int addr = g * 8192 + (ks * 2) * 512 + lane * 8 + j;  // f16 units
    Epk[addr] = h;        // hi plane (p=0)
    Epk[addr + 512] = l;  // lo plane (p=1)
    float sq = e * e;
#pragma unroll
    for (int off = 32; off > 0; off >>= 1) sq += __shfl_down(sq, off, 64);
    __shared__ float s2[2];
    if ((d & 63) == 0) s2[d >> 6] = sq;
    __syncthreads();
    if (d == 0) enorm[k] = s2[0] + s2[1];
}

// Fused MFMA dist + argmin + gather + loss.
// r14 (this round): r13 (16 waves/CU, 2 code streams) regressed to 78.5 ->
// free-running waves only share L1 on ONE stream; r11 (8 waves/CU, one
// stream) = 59us is the streaming sweet spot (rows/wave x waves/CU = 256 is
// a hard trade). Remaining lever at 59us: MFMA pipe 932 cyc/SIMD/step (42%)
// + per-step instruction churn. Switch 16x16x32 -> 32x32x16: +20% MFMA rate
// (m119 2495 vs m06 2075 TF), HALF the MFMA instructions (24 vs 48 per wave
// per 32 codes), half the loop iterations; same B-bytes/loads/argmin.
// Wave owns 32 rows as one M=32 tile (NSUB gone). 3 independent acc chains
// (hh, lo*h, h*lo) keep the matrix pipe fed at 2 waves/SIMD. B prefetch at
// half-step granularity (full-step distance per half): A 64 + B 64 + acc 48
// + best 32 VGPR ~= 230, fits (256,2). C layout (m74/m101): col=lane&31,
// row=(r&3)+8*(r>>2)+4*(lane>>5). r3 lesson: arrays only with fully-unrolled
// literal indices.
__global__ __launch_bounds__(256, 2) void vq_kernel(const float* __restrict__ z,
                                                    const _Float16* __restrict__ Epk,
                                                    const float* __restrict__ enorm,
                                                    const float* __restrict__ E,
                                                    float* __restrict__ out,
                                                    float* __restrict__ loss) {
    const int t = threadIdx.x;
    const int lane = t & 63;
    const int wave = t >> 6;     // rows [wave*32, wave*32+32)
    const int mrow = lane & 31;  // A row within wave tile / B,C code col
    const int hi = lane >> 5;    // k-group for A/B; row-group for C

    __shared__ __attribute__((aligned(16))) float s_enorm[NCODES];  // 4 KB
    __shared__ int s_ind[MTILE];
    __shared__ float s_wsum[4];

    // one-time enorm -> LDS (vectorized, 256 thr x 16 B)
    *(float4*)&s_enorm[t * 4] = ((const float4*)enorm)[t];

    // Load half HF (8 KB: 4 ks x 2 planes) of step ST's tile into DST[8]
    // (DST[ksl*2+p]); each frag is one coalesced 1 KB global_load_dwordx4.
#define LOADH(ST, HF, DST)                                                                  \
    {                                                                                       \
        const char* gb = (const char*)Epk + (size_t)(ST)*TILE_BYTES + (HF)*8192 + lane * 16; \
        DST[0] = *(const f16x8*)(gb);                                                       \
        DST[1] = *(const f16x8*)(gb + 1024);                                                \
        DST[2] = *(const f16x8*)(gb + 2048);                                                \
        DST[3] = *(const f16x8*)(gb + 3072);                                                \
        DST[4] = *(const f16x8*)(gb + 4096);                                                \
        DST[5] = *(const f16x8*)(gb + 5120);                                                \
        DST[6] = *(const f16x8*)(gb + 6144);                                                \
        DST[7] = *(const f16x8*)(gb + 7168);                                                \
    }

    f16x8 BA[8], BB[8];
    LOADH(0, 0, BA)  // both halves of step 0 fly under A-prep
    LOADH(0, 1, BB)

    // ---- A fragments: wave's 32 rows, K=128, scaled by -2, f16 hi/lo split.
    // A layout (32x32x16): lane holds A[m=lane&31][k=ks*16 + (lane>>5)*8 + j].
    f16x8 Ah[8], Al[8];
    float znp = 0.f;
    const int rowbase = blockIdx.x * MTILE + wave * 32;
    {
        const float* zp = z + (size_t)(rowbase + mrow) * DIM + hi * 8;
#pragma unroll
        for (int ks = 0; ks < 8; ++ks) {
            float4 v0 = *(const float4*)(zp + ks * 16);
            float4 v1 = *(const float4*)(zp + ks * 16 + 4);
            float zv[8] = {v0.x, v0.y, v0.z, v0.w, v1.x, v1.y, v1.z, v1.w};
#pragma unroll
            for (int j = 0; j < 8; ++j) {
                znp = fmaf(zv[j], zv[j], znp);
                float tt = -2.f * zv[j];
                _Float16 h = (_Float16)tt;
                Ah[ks][j] = h;
                Al[ks][j] = (_Float16)(tt - (float)h);
            }
        }
    }
    // full row norm: lane and lane^32 cover complementary k-halves of row mrow
    znp += __shfl_xor(znp, 32, 64);

    float bestv[16];
    int besti[16];
#pragma unroll
    for (int r = 0; r < 16; ++r) {
        bestv[r] = FLT_MAX;
        besti[r] = 0;
    }

    __syncthreads();  // s_enorm visible (only barrier before the epilogue)

    float eC = s_enorm[mrow];

    // 12 MFMAs of one half: 3 chains per ks-slice (hh->accA, lo*h->accB,
    // h*lo->accC); all independent -> pipe stays fed at 2 waves/SIMD.
#define HALF(H, REG)                                                                            \
    _Pragma("unroll") for (int ksl = 0; ksl < 4; ++ksl) {                                       \
        accA = __builtin_amdgcn_mfma_f32_32x32x16_f16(Ah[(H)*4 + ksl], REG[ksl * 2], accA, 0, 0, 0); \
        accB = __builtin_amdgcn_mfma_f32_32x32x16_f16(Al[(H)*4 + ksl], REG[ksl * 2], accB, 0, 0, 0); \
        accC = __builtin_amdgcn_mfma_f32_32x32x16_f16(Ah[(H)*4 + ksl], REG[ksl * 2 + 1], accC, 0, 0, 0); \
    }

    for (int st = 0; st < NSTEPS; ++st) {
        const float eN = (st < NSTEPS - 1) ? s_enorm[(st + 1) * 32 + mrow] : 0.f;
        f32x16 accA, accB, accC;
#pragma unroll
        for (int r = 0; r < 16; ++r) {
            accA[r] = eC;  // fold ||E||^2 into the hh chain
            accB[r] = 0.f;
            accC[r] = 0.f;
        }
        __builtin_amdgcn_s_setprio(1);
        HALF(0, BA)
        __builtin_amdgcn_s_setprio(0);
        if (st < NSTEPS - 1) LOADH(st + 1, 0, BA)  // next half0: full-step distance
        __builtin_amdgcn_s_setprio(1);
        HALF(1, BB)
        __builtin_amdgcn_s_setprio(0);
        if (st < NSTEPS - 1) LOADH(st + 1, 1, BB)  // next half1: full-step distance
        const int n_ = st * 32 + mrow;
        // C layout: col = lane&31 (code), row = (r&3) + 8*(r>>2) + 4*hi
#pragma unroll
        for (int r = 0; r < 16; ++r) {
            const float d = (accA[r] + accB[r]) + accC[r];
            if (d < bestv[r]) {  // strict <, ascending n per lane => first-index
                bestv[r] = d;
                besti[r] = n_;
            }
        }
        eC = eN;
    }
#undef HALF
#undef LOADH

    // ---- cross-lane argmin: the 32 lanes of a hi-group hold the same 16 rows
    // for 32 different codes; xor butterfly (1..16) stays in-group; lexicographic
    // (v,i) merge == global first-index rule.
#pragma unroll
    for (int r = 0; r < 16; ++r) {
        float v = bestv[r];
        int i = besti[r];
#pragma unroll
        for (int m = 1; m <= 16; m <<= 1) {
            float ov = __shfl_xor(v, m, 64);
            int oi = __shfl_xor(i, m, 64);
            if (ov < v || (ov == v && oi < i)) {
                v = ov;
                i = oi;
            }
        }
        bestv[r] = v;
        besti[r] = i;
    }

    // winner lanes (mrow==0): lane 0 owns hi=0 rows, lane 32 owns hi=1 rows.
    // znorm of row rl lives in lane rl (post-fold); shfl is lane-divergent-src ok.
    float lp = 0.f;
#pragma unroll
    for (int r = 0; r < 16; ++r) {
        const int rl = (r & 3) + 8 * (r >> 2) + 4 * hi;
        const float zz = __shfl(znp, rl, 64);
        if (mrow == 0) {
            s_ind[wave * 32 + rl] = besti[r];
            lp += zz + bestv[r];  // ||z-E||^2 = ||z||^2 + dist'
        }
    }
    lp += __shfl_xor(lp, 32, 64);  // lane0 += lane32 partial
    if (lane == 0) s_wsum[wave] = lp;
    __syncthreads();
    if (t == 0)
        atomicAdd(loss, (s_wsum[0] + s_wsum[1] + s_wsum[2] + s_wsum[3]) * LOSS_SCALE);

    // ---- gather-write z_q (STE forward == z_q), float4 coalesced, E is L2-hot
    const float4* E4 = (const float4*)E;
    float4* out4 = (float4*)(out + (size_t)blockIdx.x * (MTILE * DIM));
#pragma unroll
    for (int i = 0; i < (MTILE * DIM) / (256 * 4); ++i) {
        const int f = t + i * 256;  // float4 index within tile
        const int r = f >> 5;       // 32 float4 per row
        const int d = f & 31;
        out4[f] = E4[(size_t)s_ind[r] * 32 + d];
    }
}

extern "C" void kernel_launch(void* const* d_in, const int* in_sizes, int n_in,
                              void* d_out, int out_size, void* d_ws, size_t ws_size,
                              hipStream_t stream) {
    const float* z = (const float*)d_in[0];  // [BN,128] fp32
    const float* E = (const float*)d_in[1];  // [1024,128] fp32
    float* out = (float*)d_out;              // [BN*128] z_q + [1] loss
    float* loss = out + (size_t)(out_size - 1);
    _Float16* Epk = (_Float16*)d_ws;                          // 512 KB packed image
    float* enorm = (float*)((char*)d_ws + (size_t)NCODES * DIM * 2 * sizeof(_Float16));  // 4 KB
    const int BN = in_sizes[0] / DIM;

    prep_kernel<<<NCODES, 128, 0, stream>>>(E, Epk, enorm, loss);
    vq_kernel<<<BN / MTILE, 256, 0, stream>>>(z, Epk, enorm, E, out, loss);
}

// Round 9
// 129.754 us; speedup vs baseline: 1.1156x; 1.1156x over previous
//
#include <hip/hip_runtime.h>
#include <hip/hip_bf16.h>
#include <cfloat>

// B=32, N=2048 -> BN=65536 rows, D=128, K=1024 codes
#define DIM 128
#define NCODES 1024
#define MTILE 128            // rows per block = 4 waves x 32 rows
#define ROWS_PER_WAVE 32
#define NSUB 2               // 16-row M-subtiles per wave
#define KSTEPS 4             // K=128 / 32
#define CODES_PER_TILE 16    // codes per step tile
#define NSTEPS 64            // 1024 codes / 16
#define TILE_F16 4096        // f16 elems per 16-code tile (8 KB: hi 2048 + lo 2048)
#define TILE_BYTES 8192
#define LOSS_SCALE (12.5f / 8388608.0f)

typedef _Float16 f16x8 __attribute__((ext_vector_type(8)));
typedef float f32x4 __attribute__((ext_vector_type(4)));

// prep: E (fp32) -> Epk (packed fragment-linear f16 hi/lo image) + enorm.
// Tile g = k>>4 holds codes g*16..g*16+15. Within a tile (f16 units):
//   addr = g*4096 + plane*2048 + ks*512 + (quad*16 + m16)*8 + j
// (ks=d>>5, quad=(d>>3)&3, j=d&7) so vq's lane l=quad*16+m16 loads its 16 B at
// tile_base + plane*4096B + ks*1024B + l*16 -> one contiguous, coalesced 1 KB
// global_load_dwordx4 per (plane,ks). Block 0 zeroes loss.
__global__ __launch_bounds__(128) void prep_kernel(const float* __restrict__ E,
                                                   _Float16* __restrict__ Epk,
                                                   float* __restrict__ enorm,
                                                   float* __restrict__ loss) {
    const int k = blockIdx.x;   // code
    const int d = threadIdx.x;  // dim
    if (k == 0 && d == 0) *loss = 0.f;
    float e = E[k * DIM + d];
    _Float16 h = (_Float16)e;
    _Float16 l = (_Float16)(e - (float)h);
    const int g = k >> 4;
    const int m16 = k & 15;
    const int ks = d >> 5, quad = (d >> 3) & 3, j = d & 7;
    const int addr = g * TILE_F16 + ks * 512 + ((quad << 4) + m16) * 8 + j;
    Epk[addr] = h;           // hi plane
    Epk[addr + 2048] = l;    // lo plane
    float sq = e * e;
#pragma unroll
    for (int off = 32; off > 0; off >>= 1) sq += __shfl_down(sq, off, 64);
    __shared__ float s2[2];
    if ((d & 63) == 0) s2[d >> 6] = sq;
    __syncthreads();
    if (d == 0) enorm[k] = s2[0] + s2[1];
}

// Fused MFMA dist + argmin + gather + loss.
// r15 (this round): r14's 32x32 shape cut MFMA cycles as predicted (51.7k vs
// 59.6k) but non-MFMA time exploded (82k->148k; f32x16 acc churn + worse
// prefetch placement) -> reverted to r11, the empirical streaming optimum
// (59us, MfmaUtil 42%). r11's remaining gap vs the overlapped floor (~31us):
// per-step sum 932 MFMA + ~509 VALU + ~1170 L2-delivery ~= measured 2213 ->
// pipes are nearly serial; symmetric waves hit the consume-wait together.
// Single delta this round: prefetch depth 1 -> 2 (three register buffer
// sets X/Y/Z, consume-distance 2 bodies ~= 2200 wave-cyc per batch). The
// consume wait becomes satisfiable even under conservative waitcnt counting;
// +32 VGPR, everything else (MFMA order, argmin, zero loop barriers,
// (256,2)) byte-identical to r11. r3 lesson: no runtime-indexed register
// arrays (period-3 rotation with named FX/FY/FZ sets).
__global__ __launch_bounds__(256, 2) void vq_kernel(const float* __restrict__ z,
                                                    const _Float16* __restrict__ Epk,
                                                    const float* __restrict__ enorm,
                                                    const float* __restrict__ E,
                                                    float* __restrict__ out,
                                                    float* __restrict__ loss) {
    const int t = threadIdx.x;
    const int lane = t & 63;
    const int wave = t >> 6;     // row-wave: rows [wave*32, wave*32+32)
    const int m16 = lane & 15;   // A row within subtile / B,C code col
    const int quad = lane >> 4;  // k-group for A/B; row-group for C

    __shared__ __attribute__((aligned(16))) float s_enorm[NCODES];  // 4 KB
    __shared__ int s_ind[MTILE];
    __shared__ float s_wsum[4];

    // one-time enorm -> LDS (vectorized, 256 thr x 16 B)
    *(float4*)&s_enorm[t * 4] = ((const float4*)enorm)[t];

    // Load step ST's 8 fragment sets (hi+lo x 4 ksteps) from global; each is
    // one coalesced 1 KB global_load_dwordx4 (lane-linear packed layout).
#define LOADF(ST, H, L)                                                              \
    {                                                                                \
        const char* gb = (const char*)Epk + (size_t)(ST)*TILE_BYTES + lane * 16;     \
        H[0] = *(const f16x8*)(gb);                                                  \
        H[1] = *(const f16x8*)(gb + 1024);                                           \
        H[2] = *(const f16x8*)(gb + 2048);                                           \
        H[3] = *(const f16x8*)(gb + 3072);                                           \
        L[0] = *(const f16x8*)(gb + 4096);                                           \
        L[1] = *(const f16x8*)(gb + 5120);                                           \
        L[2] = *(const f16x8*)(gb + 6144);                                           \
        L[3] = *(const f16x8*)(gb + 7168);                                           \
    }

    f16x8 FXh[KSTEPS], FXl[KSTEPS], FYh[KSTEPS], FYl[KSTEPS], FZh[KSTEPS], FZl[KSTEPS];
    LOADF(0, FXh, FXl)  // steps 0,1 in flight under A-prep below
    LOADF(1, FYh, FYl)

    // ---- A fragments: this wave's 32 rows, K=128, scaled by -2, f16 hi/lo.
    // A layout (16x16x32): lane holds A[m=lane&15][k=quad*8+j], j=0..7.
    f16x8 Ahi[NSUB][KSTEPS], Alo[NSUB][KSTEPS];
    float znp[NSUB] = {0.f, 0.f};
    const int rowbase = blockIdx.x * MTILE + wave * ROWS_PER_WAVE;
#pragma unroll
    for (int s = 0; s < NSUB; ++s) {
        const int row = rowbase + s * 16 + m16;
        const float* zp = z + (size_t)row * DIM + quad * 8;
#pragma unroll
        for (int ks = 0; ks < KSTEPS; ++ks) {
            float4 v0 = *(const float4*)(zp + ks * 32);
            float4 v1 = *(const float4*)(zp + ks * 32 + 4);
            float zv[8] = {v0.x, v0.y, v0.z, v0.w, v1.x, v1.y, v1.z, v1.w};
#pragma unroll
            for (int j = 0; j < 8; ++j) {
                znp[s] = fmaf(zv[j], zv[j], znp[s]);
                float tt = -2.f * zv[j];
                _Float16 h = (_Float16)tt;
                Ahi[s][ks][j] = h;
                Alo[s][ks][j] = (_Float16)(tt - (float)h);
            }
        }
    }
    // znorm per row, kept in registers: after the two xors every lane holds
    // the full ||z_row||^2 for row s*16 + m16 of this wave.
#pragma unroll
    for (int s = 0; s < NSUB; ++s) {
        znp[s] += __shfl_xor(znp[s], 16, 64);
        znp[s] += __shfl_xor(znp[s], 32, 64);
    }

    float bestv[NSUB][4];
    int besti[NSUB][4];
#pragma unroll
    for (int s = 0; s < NSUB; ++s)
#pragma unroll
        for (int r = 0; r < 4; ++r) {
            bestv[s][r] = FLT_MAX;
            besti[s][r] = 0;
        }

    __syncthreads();  // s_enorm visible (only barrier before the epilogue)

    float eX = s_enorm[m16];
    float eY = s_enorm[CODES_PER_TILE + m16];
    float eZ = 0.f;

    // Step body: 24 MFMAs on current frags (CH,CL,CE); loads for ST+2 issue
    // into the buffer freed THIS body (NH,NL,NE) -> every batch has ~2 bodies
    // to land before its consume (no barriers; waits are per-wave counted).
#define BODY(ST, CH, CL, CE, NH, NL, NE)                                                      \
    {                                                                                         \
        const int st2_ = (ST) + 2;                                                            \
        if (st2_ < NSTEPS) {                                                                  \
            LOADF(st2_, NH, NL)                                                               \
            NE = s_enorm[st2_ * CODES_PER_TILE + m16];                                        \
        }                                                                                     \
        f32x4 acc0 = {CE, CE, CE, CE}, acc1 = {CE, CE, CE, CE};                               \
        __builtin_amdgcn_s_setprio(1);                                                        \
        _Pragma("unroll") for (int ks = 0; ks < KSTEPS; ++ks) {                               \
            acc0 = __builtin_amdgcn_mfma_f32_16x16x32_f16(Ahi[0][ks], CH[ks], acc0, 0, 0, 0); \
            acc1 = __builtin_amdgcn_mfma_f32_16x16x32_f16(Ahi[1][ks], CH[ks], acc1, 0, 0, 0); \
            acc0 = __builtin_amdgcn_mfma_f32_16x16x32_f16(Ahi[0][ks], CL[ks], acc0, 0, 0, 0); \
            acc1 = __builtin_amdgcn_mfma_f32_16x16x32_f16(Ahi[1][ks], CL[ks], acc1, 0, 0, 0); \
            acc0 = __builtin_amdgcn_mfma_f32_16x16x32_f16(Alo[0][ks], CH[ks], acc0, 0, 0, 0); \
            acc1 = __builtin_amdgcn_mfma_f32_16x16x32_f16(Alo[1][ks], CH[ks], acc1, 0, 0, 0); \
        }                                                                                     \
        __builtin_amdgcn_s_setprio(0);                                                        \
        const int n_ = (ST)*CODES_PER_TILE + m16;                                             \
        /* C layout: col = lane&15 (code), row = quad*4 + r */                                \
        _Pragma("unroll") for (int r = 0; r < 4; ++r) {                                       \
            if (acc0[r] < bestv[0][r]) { bestv[0][r] = acc0[r]; besti[0][r] = n_; }           \
            if (acc1[r] < bestv[1][r]) { bestv[1][r] = acc1[r]; besti[1][r] = n_; }           \
        }                                                                                     \
    }

    // Rotation (period 3): consume X,Y,Z,...; body(ST) restages into the
    // buffer that held ST (freed as it is consumed) for step ST+2... i.e.
    // consume X -> load into Z? No: target holds (ST+2); (ST+2)%3 slot.
    // st%3: 0->X 1->Y 2->Z; load target (st+2)%3: 0-body->Z, 1-body->X, 2-body->Y.
    for (int st = 0; st < NSTEPS - 1; st += 3) {
        BODY(st, FXh, FXl, eX, FZh, FZl, eZ)
        BODY(st + 1, FYh, FYl, eY, FXh, FXl, eX)
        BODY(st + 2, FZh, FZl, eZ, FYh, FYl, eY)
    }
    BODY(NSTEPS - 1, FXh, FXl, eX, FYh, FYl, eY)  // 63%3==0 -> X; no load (st2_=65)
#undef BODY
#undef LOADF

    // ---- in-wave argmin across the 16 m16-lanes (xor butterflies stay
    // in-quad; lexicographic (v,i) merge == global first-index rule; after the
    // butterfly ALL 16 lanes of a group hold the winner)
#pragma unroll
    for (int s = 0; s < NSUB; ++s)
#pragma unroll
        for (int r = 0; r < 4; ++r) {
            float v = bestv[s][r];
            int i = besti[s][r];
#pragma unroll
            for (int m = 1; m <= 8; m <<= 1) {
                float ov = __shfl_xor(v, m, 64);
                int oi = __shfl_xor(i, m, 64);
                if (ov < v || (ov == v && oi < i)) {
                    v = ov;
                    i = oi;
                }
            }
            bestv[s][r] = v;
            besti[s][r] = i;
        }

    // winner lane per quad owns rows quad*4+r (+s*16); loss partial uses
    // znorm shfl'd from the lane whose m16 == quad*4+r.
    float lp = 0.f;
#pragma unroll
    for (int s = 0; s < NSUB; ++s)
#pragma unroll
        for (int r = 0; r < 4; ++r) {
            const float zz = __shfl(znp[s], quad * 4 + r, 16);
            if (m16 == 0) {
                const int row = wave * ROWS_PER_WAVE + s * 16 + quad * 4 + r;
                s_ind[row] = besti[s][r];
                lp += zz + bestv[s][r];  // ||z-E||^2 = ||z||^2 + dist'
            }
        }
    lp += __shfl_xor(lp, 16, 64);  // lanes {0,16,32,48} hold partials
    lp += __shfl_xor(lp, 32, 64);
    if (lane == 0) s_wsum[wave] = lp;
    __syncthreads();
    if (t == 0)
        atomicAdd(loss, (s_wsum[0] + s_wsum[1] + s_wsum[2] + s_wsum[3]) * LOSS_SCALE);

    // ---- gather-write z_q (STE forward == z_q), float4 coalesced, E is L2-hot
    const float4* E4 = (const float4*)E;
    float4* out4 = (float4*)(out + (size_t)blockIdx.x * (MTILE * DIM));
#pragma unroll
    for (int i = 0; i < (MTILE * DIM) / (256 * 4); ++i) {
        const int f = t + i * 256;  // float4 index within tile
        const int r = f >> 5;       // 32 float4 per row
        const int d = f & 31;
        out4[f] = E4[(size_t)s_ind[r] * 32 + d];
    }
}

extern "C" void kernel_launch(void* const* d_in, const int* in_sizes, int n_in,
                              void* d_out, int out_size, void* d_ws, size_t ws_size,
                              hipStream_t stream) {
    const float* z = (const float*)d_in[0];  // [BN,128] fp32
    const float* E = (const float*)d_in[1];  // [1024,128] fp32
    float* out = (float*)d_out;              // [BN*128] z_q + [1] loss
    float* loss = out + (size_t)(out_size - 1);
    _Float16* Epk = (_Float16*)d_ws;                          // 512 KB packed image
    float* enorm = (float*)((char*)d_ws + (size_t)NCODES * DIM * 2 * sizeof(_Float16));  // 4 KB
    const int BN = in_sizes[0] / DIM;

    prep_kernel<<<NCODES, 128, 0, stream>>>(E, Epk, enorm, loss);
    vq_kernel<<<BN / MTILE, 256, 0, stream>>>(z, Epk, enorm, E, out, loss);
}